// Round 5
// baseline (901.879 us; speedup 1.0000x reference)
//
#include <hip/hip_runtime.h>
#include <hip/hip_bf16.h>
#include <stdint.h>

// Problem constants (from reference setup_inputs)
#define B_   8
#define NS_  8192
#define E_   32
#define NT_  8192
#define NH_  10

// ---------------------------------------------------------------------------
// Kernel A: per-target-row top-10 smallest d = sqrt(lon^2+lat^2).
// (VERIFIED PASSING — unchanged.)
// ---------------------------------------------------------------------------
__global__ __launch_bounds__(256) void topk_kernel(
    const float* __restrict__ rel_lon, const float* __restrict__ rel_lat,
    float* __restrict__ out_d, float* __restrict__ out_lon,
    float* __restrict__ out_lat, int* __restrict__ idx_out)
{
  const int wave = threadIdx.x >> 6;
  const int lane = threadIdx.x & 63;
  const int t = blockIdx.x * 4 + wave;
  const float* lon_row = rel_lon + (size_t)t * NS_;
  const float* lat_row = rel_lat + (size_t)t * NS_;

  unsigned long long top[NH_];
#pragma unroll
  for (int i = 0; i < NH_; ++i) top[i] = ~0ull;

  for (int c = 0; c < NS_; c += 256) {
    const int s = c + lane * 4;
    const float4 lo4 = *(const float4*)(lon_row + s);
    const float4 la4 = *(const float4*)(lat_row + s);
    const float lons[4] = {lo4.x, lo4.y, lo4.z, lo4.w};
    const float lats[4] = {la4.x, la4.y, la4.z, la4.w};
#pragma unroll
    for (int j = 0; j < 4; ++j) {
      const float d = __fsqrt_rn(__fadd_rn(__fmul_rn(lons[j], lons[j]),
                                           __fmul_rn(lats[j], lats[j])));
      unsigned long long p =
          ((unsigned long long)__float_as_uint(d) << 32) | (unsigned)(s + j);
      if (p < top[NH_ - 1]) {
#pragma unroll
        for (int i = 0; i < NH_; ++i) {
          const bool lt = p < top[i];
          const unsigned long long mn = lt ? p : top[i];
          const unsigned long long mx = lt ? top[i] : p;
          top[i] = mn;
          p = mx;
        }
      }
    }
  }

  unsigned long long resv = ~0ull;
  unsigned long long cur = top[0];
#pragma unroll
  for (int k = 0; k < NH_; ++k) {
    unsigned long long m = cur;
#pragma unroll
    for (int off = 32; off > 0; off >>= 1) {
      const unsigned long long o = __shfl_xor(m, off, 64);
      m = o < m ? o : m;
    }
    if (cur == m) {
#pragma unroll
      for (int i = 0; i < NH_ - 1; ++i) top[i] = top[i + 1];
      top[NH_ - 1] = ~0ull;
      cur = top[0];
    }
    if (lane == k) resv = m;
  }

  if (lane < NH_) {
    const unsigned s = (unsigned)(resv & 0xffffffffu);
    const float d = __uint_as_float((unsigned)(resv >> 32));
    out_d[t * NH_ + lane] = d;
    idx_out[t * NH_ + lane] = (int)s;
    out_lon[t * NH_ + lane] = lon_row[s];
    out_lat[t * NH_ + lane] = lat_row[s];
  }
}

// ---------------------------------------------------------------------------
// Kernel B: x_nearest gather. (VERIFIED PASSING — unchanged.)
// ---------------------------------------------------------------------------
__global__ __launch_bounds__(256) void gather_kernel(
    const float* __restrict__ x, const int* __restrict__ idxbuf,
    float* __restrict__ out_xn)
{
  const int t = blockIdx.x;
  __shared__ int sidx[NH_];
  if (threadIdx.x < NH_) sidx[threadIdx.x] = idxbuf[t * NH_ + threadIdx.x];
  __syncthreads();
  for (int i = threadIdx.x; i < B_ * NH_ * (E_ / 4); i += 256) {  // 640 items
    const int e4 = i & 7;
    const int k = (i >> 3) % NH_;
    const int b = (i >> 3) / NH_;
    const int s = sidx[k];
    const float4 v = *(const float4*)(x + ((size_t)b * NS_ + s) * E_ + e4 * 4);
    *(float4*)(out_xn + (((size_t)b * NT_ + t) * NH_ + k) * E_ + e4 * 4) = v;
  }
}

// ---------------------------------------------------------------------------
// Kernel C: x_inter, normalization folded in.
// STRICT f32 replication of numpy+OpenBLAS (contraction disabled via pragma;
// HIP's default -ffp-contract=fast silently fused rounds 2-4's "strict" ops):
//   t2 = rn(rn(tx^2)+rn(ty^2)), s2 likewise   (np **2 + sum: never fused)
//   dot = fma(ty,sy, rn(tx*sx))               (OpenBLAS ascending-k fma ukernel)
//   d2 = rn(rn(t2+s2) - 2*dot)                (x2 exact; commutes w/ (2ct)@csT)
//   d = sqrt_rn(max(d2,1e-12)); r = 1.0f/(d+1e-10)  (IEEE divide)
// ---------------------------------------------------------------------------
#define TT_  64
#define BET_ 128
#define KS_  64

__global__ __launch_bounds__(256) void xinter_kernel(
    const float* __restrict__ x, const float* __restrict__ cs,
    const float* __restrict__ ct, float* __restrict__ out_xi)
{
#pragma clang fp contract(off)
  __shared__ float Xs[KS_][BET_];   // 32 KB
  __shared__ float Rs[KS_][TT_];    // 16 KB
  __shared__ float RsumP[4][TT_];   // 1 KB

  const int tid = threadIdx.x;
  const int t0  = blockIdx.x * TT_;
  const int be0 = blockIdx.y * BET_;

  // ---- staging roles: thread stages r for target column scol, 16 s-rows
  const int scol  = tid & 63;
  const int srow0 = (tid >> 6) * 16;
  const float2 ctv = ((const float2*)ct)[t0 + scol];
  const float tx2 = ctv.x * ctv.x;          // strict rn (contract off)
  const float ty2 = ctv.y * ctv.y;
  const float t2  = tx2 + ty2;
  float rpart = 0.f;   // this thread's partial sum of r for column scol

  // ---- compute roles: thread owns t rows ty*8..+7, be cols tx*4..+3
  const int tx = tid & 31;
  const int ty = tid >> 5;

  float acc[8][4];
#pragma unroll
  for (int i = 0; i < 8; ++i)
#pragma unroll
    for (int j = 0; j < 4; ++j) acc[i][j] = 0.f;

  for (int sc = 0; sc < NS_; sc += KS_) {
    __syncthreads();
    // stage Rs[s][t]: 64s x 64t, 16 values/thread (strict v5 arithmetic)
#pragma unroll
    for (int j = 0; j < 16; ++j) {
      const int sl = srow0 + j;
      const float2 csv = ((const float2*)cs)[sc + sl];
      const float sx2 = csv.x * csv.x;      // strict rn
      const float sy2 = csv.y * csv.y;
      const float s2  = sx2 + sy2;
      const float p0  = ctv.x * csv.x;      // strict rn product, k=0
      const float dot = fmaf(ctv.y, csv.y, p0);  // explicit fma, k=1
      const float ts  = t2 + s2;            // strict rn
      float d2 = ts - 2.0f * dot;           // 2*dot exact; sub strict rn
      d2 = fmaxf(d2, 1e-12f);
      const float den = __builtin_sqrtf(d2) + 1e-10f;  // rn sqrt, rn add
      const float r = 1.0f / den;           // IEEE divide
      Rs[sl][scol] = r;
      rpart += r;
    }
    // stage Xs[s][be]: 64s x 128be, 8 float4/thread
#pragma unroll
    for (int p = 0; p < 8; ++p) {
      const int sl  = (tid >> 5) + p * 8;
      const int bel = (tid & 31) * 4;
      const int be  = be0 + bel;
      const int b   = be >> 5;
      const int e   = be & 31;
      *(float4*)&Xs[sl][bel] =
          *(const float4*)(x + ((size_t)b * NS_ + (sc + sl)) * E_ + e);
    }
    __syncthreads();
    // compute: 32 fma + 3 ds_read_b128 per sl per thread
#pragma unroll 4
    for (int sl = 0; sl < KS_; ++sl) {
      const float4 xv = *(const float4*)&Xs[sl][tx * 4];
      const float4 r0 = *(const float4*)&Rs[sl][ty * 8];
      const float4 r1 = *(const float4*)&Rs[sl][ty * 8 + 4];
      const float rr[8] = {r0.x, r0.y, r0.z, r0.w, r1.x, r1.y, r1.z, r1.w};
#pragma unroll
      for (int i = 0; i < 8; ++i) {
        acc[i][0] = fmaf(rr[i], xv.x, acc[i][0]);
        acc[i][1] = fmaf(rr[i], xv.y, acc[i][1]);
        acc[i][2] = fmaf(rr[i], xv.z, acc[i][2]);
        acc[i][3] = fmaf(rr[i], xv.w, acc[i][3]);
      }
    }
  }

  // ---- reduce per-target r sums across the 4 row-group threads
  __syncthreads();
  RsumP[tid >> 6][scol] = rpart;
  __syncthreads();

  // ---- normalize + write out (float4 per t row)
  const int be = be0 + tx * 4;
  const int b  = be >> 5;
  const int e  = be & 31;
#pragma unroll
  for (int i = 0; i < 8; ++i) {
    const int tc = ty * 8 + i;
    const float rsum =
        (RsumP[0][tc] + RsumP[1][tc]) + (RsumP[2][tc] + RsumP[3][tc]);
    const float rinv = 1.0f / rsum;
    float4 o;
    o.x = acc[i][0] * rinv;
    o.y = acc[i][1] * rinv;
    o.z = acc[i][2] * rinv;
    o.w = acc[i][3] * rinv;
    *(float4*)(out_xi + ((size_t)b * NT_ + (t0 + tc)) * E_ + e) = o;
  }
}

// ---------------------------------------------------------------------------
extern "C" void kernel_launch(void* const* d_in, const int* in_sizes, int n_in,
                              void* d_out, int out_size, void* d_ws,
                              size_t ws_size, hipStream_t stream)
{
  const float* x       = (const float*)d_in[0];
  const float* rel_lon = (const float*)d_in[1];
  const float* rel_lat = (const float*)d_in[2];
  const float* cs      = (const float*)d_in[3];
  const float* ct      = (const float*)d_in[4];

  float* out = (float*)d_out;
  float* out_xn  = out;                                // (8,8192,10,32)
  float* out_xi  = out + (size_t)B_ * NT_ * NH_ * E_;  // (8,8192,32)
  float* out_d   = out_xi + (size_t)B_ * NT_ * E_;     // (8192,10)
  float* out_lon = out_d + (size_t)NT_ * NH_;
  float* out_lat = out_lon + (size_t)NT_ * NH_;

  int* idxbuf = (int*)d_ws;  // 8192*10*4 = 327,680 B

  topk_kernel<<<NT_ / 4, 256, 0, stream>>>(rel_lon, rel_lat, out_d, out_lon,
                                           out_lat, idxbuf);
  gather_kernel<<<NT_, 256, 0, stream>>>(x, idxbuf, out_xn);
  xinter_kernel<<<dim3(NT_ / TT_, (B_ * E_) / BET_), 256, 0, stream>>>(
      x, cs, ct, out_xi);
}

// Round 7
// 516.725 us; speedup vs baseline: 1.7454x; 1.7454x over previous
//
#include <hip/hip_runtime.h>
#include <hip/hip_bf16.h>
#include <stdint.h>

#define B_   8
#define NS_  8192
#define E_   32
#define NT_  8192
#define NH_  10

typedef __bf16 bf16x8 __attribute__((ext_vector_type(8)));
typedef float  f32x4  __attribute__((ext_vector_type(4)));
typedef unsigned short ushort8 __attribute__((ext_vector_type(8)));

static __device__ inline unsigned short f2bf(float f) {
  __hip_bfloat16 h = __float2bfloat16(f);
  return *reinterpret_cast<unsigned short*>(&h);
}
static __device__ inline float bf2f(unsigned short u) {
  __hip_bfloat16 h;
  *reinterpret_cast<unsigned short*>(&h) = u;
  return __bfloat162float(h);
}

// ---------------------------------------------------------------------------
// Kernel A: per-target-row top-10 smallest d. (VERIFIED PASSING — unchanged.)
// ---------------------------------------------------------------------------
__global__ __launch_bounds__(256) void topk_kernel(
    const float* __restrict__ rel_lon, const float* __restrict__ rel_lat,
    float* __restrict__ out_d, float* __restrict__ out_lon,
    float* __restrict__ out_lat, int* __restrict__ idx_out)
{
  const int wave = threadIdx.x >> 6;
  const int lane = threadIdx.x & 63;
  const int t = blockIdx.x * 4 + wave;
  const float* lon_row = rel_lon + (size_t)t * NS_;
  const float* lat_row = rel_lat + (size_t)t * NS_;

  unsigned long long top[NH_];
#pragma unroll
  for (int i = 0; i < NH_; ++i) top[i] = ~0ull;

  for (int c = 0; c < NS_; c += 256) {
    const int s = c + lane * 4;
    const float4 lo4 = *(const float4*)(lon_row + s);
    const float4 la4 = *(const float4*)(lat_row + s);
    const float lons[4] = {lo4.x, lo4.y, lo4.z, lo4.w};
    const float lats[4] = {la4.x, la4.y, la4.z, la4.w};
#pragma unroll
    for (int j = 0; j < 4; ++j) {
      const float d = __fsqrt_rn(__fadd_rn(__fmul_rn(lons[j], lons[j]),
                                           __fmul_rn(lats[j], lats[j])));
      unsigned long long p =
          ((unsigned long long)__float_as_uint(d) << 32) | (unsigned)(s + j);
      if (p < top[NH_ - 1]) {
#pragma unroll
        for (int i = 0; i < NH_; ++i) {
          const bool lt = p < top[i];
          const unsigned long long mn = lt ? p : top[i];
          const unsigned long long mx = lt ? top[i] : p;
          top[i] = mn;
          p = mx;
        }
      }
    }
  }

  unsigned long long resv = ~0ull;
  unsigned long long cur = top[0];
#pragma unroll
  for (int k = 0; k < NH_; ++k) {
    unsigned long long m = cur;
#pragma unroll
    for (int off = 32; off > 0; off >>= 1) {
      const unsigned long long o = __shfl_xor(m, off, 64);
      m = o < m ? o : m;
    }
    if (cur == m) {
#pragma unroll
      for (int i = 0; i < NH_ - 1; ++i) top[i] = top[i + 1];
      top[NH_ - 1] = ~0ull;
      cur = top[0];
    }
    if (lane == k) resv = m;
  }

  if (lane < NH_) {
    const unsigned s = (unsigned)(resv & 0xffffffffu);
    const float d = __uint_as_float((unsigned)(resv >> 32));
    out_d[t * NH_ + lane] = d;
    idx_out[t * NH_ + lane] = (int)s;
    out_lon[t * NH_ + lane] = lon_row[s];
    out_lat[t * NH_ + lane] = lat_row[s];
  }
}

// ---------------------------------------------------------------------------
// Kernel B: x_nearest gather. (VERIFIED PASSING — unchanged. Runs LAST.)
// ---------------------------------------------------------------------------
__global__ __launch_bounds__(256) void gather_kernel(
    const float* __restrict__ x, const int* __restrict__ idxbuf,
    float* __restrict__ out_xn)
{
  const int t = blockIdx.x;
  __shared__ int sidx[NH_];
  if (threadIdx.x < NH_) sidx[threadIdx.x] = idxbuf[t * NH_ + threadIdx.x];
  __syncthreads();
  for (int i = threadIdx.x; i < B_ * NH_ * (E_ / 4); i += 256) {  // 640 items
    const int e4 = i & 7;
    const int k = (i >> 3) % NH_;
    const int b = (i >> 3) / NH_;
    const int s = sidx[k];
    const float4 v = *(const float4*)(x + ((size_t)b * NS_ + s) * E_ + e4 * 4);
    *(float4*)(out_xn + (((size_t)b * NT_ + t) * NH_ + k) * E_ + e4 * 4) = v;
  }
}

// ---------------------------------------------------------------------------
// Kernel P: x (f32 [b][s][e]) -> XT (bf16 [be=b*32+e][s]), LDS tile transpose.
// FIXED: each thread now writes TWO ushort8 (full 32x128 tile coverage;
// round 6 wrote only half the columns).
// ---------------------------------------------------------------------------
__global__ __launch_bounds__(256) void xprep_kernel(
    const float* __restrict__ x, unsigned short* __restrict__ XT)
{
  __shared__ __align__(16) unsigned short T[32][128];
  const int b = blockIdx.y;
  const int s0 = blockIdx.x * 128;
  const int tid = threadIdx.x;
  const int eq = tid & 7, slq = tid >> 3;
#pragma unroll
  for (int r4 = 0; r4 < 4; ++r4) {
    const int sl = r4 * 32 + slq;
    const float4 v = *(const float4*)&x[((size_t)b * NS_ + s0 + sl) * E_ + eq * 4];
    T[eq * 4 + 0][sl] = f2bf(v.x);
    T[eq * 4 + 1][sl] = f2bf(v.y);
    T[eq * 4 + 2][sl] = f2bf(v.z);
    T[eq * 4 + 3][sl] = f2bf(v.w);
  }
  __syncthreads();
  const int r = tid >> 3, cq = tid & 7;
  *(ushort8*)&XT[(size_t)(b * 32 + r) * NS_ + s0 + cq * 16] =
      *(const ushort8*)&T[r][cq * 16];
  *(ushort8*)&XT[(size_t)(b * 32 + r) * NS_ + s0 + cq * 16 + 8] =
      *(const ushort8*)&T[r][cq * 16 + 8];
}

// ---------------------------------------------------------------------------
// Kernel C: x_inter via bf16 MFMA.
//   out[be=b*32+e][t] = (sum_s XT[be][s] * r(t,s)) / rsum[t]
// M=256 (be), N=32 (two 16-t n-tiles), K=8192 (s). 8 waves = 4 mg x 2 ng;
// each wave owns FULL K for its (m-range, n-tile) -> complete accumulator,
// disjoint output regions (fixes round-6 kq write race).
// A-frag from LDS Xl[kidx][be][8] (identical per-lane s-indexing as B-frag
// => correctness independent of HW k-permutation). B-frag (r values)
// generated in-register; rsum is lane-local, reduced via shfl-xor 16/32.
// d2 = round-5 bit-exact strict sequence (contract off); r = rsq(d2).
// ---------------------------------------------------------------------------
__global__ __launch_bounds__(512) void xinter_mfma(
    const unsigned short* __restrict__ XT, const float* __restrict__ cs,
    const float* __restrict__ ct, float* __restrict__ out_xi)
{
#pragma clang fp contract(off)
  __shared__ __align__(16) unsigned short Xl[8][256][8];  // 32 KB

  const int tid = threadIdx.x;
  const int w = tid >> 6, l = tid & 63;
  const int mg = w >> 1, ng = w & 1;
  const int lcol = l & 15, lkg = l >> 4;
  const int t0 = blockIdx.x * 32;
  const int t = t0 + ng * 16 + lcol;

  const float2 ctv = ((const float2*)ct)[t];
  const float t2 = ctv.x * ctv.x + ctv.y * ctv.y;  // strict rn (contract off)

  f32x4 acc[4];
#pragma unroll
  for (int m = 0; m < 4; ++m)
#pragma unroll
    for (int j = 0; j < 4; ++j) acc[m][j] = 0.f;
  float rsum = 0.f;

  for (int sc = 0; sc < NS_; sc += 64) {
    __syncthreads();
    // stage: wave w fills Xl[w][be][0..7] = XT[be][sc + w*8 .. +8]
    {
      const unsigned short* gsrc = XT + (size_t)l * NS_ + (sc + w * 8);
#pragma unroll
      for (int bg = 0; bg < 4; ++bg) {
        __builtin_amdgcn_global_load_lds(
            (const __attribute__((address_space(1))) void*)(gsrc +
                (size_t)bg * 64 * NS_),
            (__attribute__((address_space(3))) void*)&Xl[w][bg * 64][0],
            16, 0, 0);
      }
    }
    __syncthreads();

#pragma unroll
    for (int half = 0; half < 2; ++half) {
      const int sbase = sc + half * 32 + lkg * 8;  // this lane's 8 s-values
      const float4 c01 = *(const float4*)&cs[2 * sbase];
      const float4 c23 = *(const float4*)&cs[2 * sbase + 4];
      const float4 c45 = *(const float4*)&cs[2 * sbase + 8];
      const float4 c67 = *(const float4*)&cs[2 * sbase + 12];
      const float sxv[8] = {c01.x, c01.z, c23.x, c23.z,
                            c45.x, c45.z, c67.x, c67.z};
      const float syv[8] = {c01.y, c01.w, c23.y, c23.w,
                            c45.y, c45.w, c67.y, c67.w};

      bf16x8 Bf;
#pragma unroll
      for (int i = 0; i < 8; ++i) {
        const float sx = sxv[i], sy = syv[i];
        const float s2 = sx * sx + sy * sy;        // strict rn
        const float p0 = ctv.x * sx;               // strict rn product, k=0
        const float dot = fmaf(ctv.y, sy, p0);     // explicit fma, k=1
        const float ts = t2 + s2;                  // strict rn
        float d2 = ts - 2.0f * dot;                // 2*dot exact; strict sub
        d2 = fmaxf(d2, 1e-12f);
        const float r = __builtin_amdgcn_rsqf(d2);
        const unsigned short ub = f2bf(r);
        Bf[i] = *reinterpret_cast<const __bf16*>(&ub);
        rsum += bf2f(ub);
      }

#pragma unroll
      for (int m = 0; m < 4; ++m) {
        const bf16x8 a =
            *(const bf16x8*)&Xl[half * 4 + lkg][(mg * 4 + m) * 16 + lcol][0];
        acc[m] = __builtin_amdgcn_mfma_f32_16x16x32_bf16(a, Bf, acc[m], 0, 0, 0);
      }
    }
  }

  // rsum: reduce across the 4 k-slice lane-groups (lkg) -> full-K sum per t.
  rsum += __shfl_xor(rsum, 16, 64);
  rsum += __shfl_xor(rsum, 32, 64);
  const float ri = 1.0f / rsum;

  // C/D layout: lane l reg j -> row(be) = lkg*4 + j, col(t) = lcol.
#pragma unroll
  for (int m = 0; m < 4; ++m) {
    const int be0 = (mg * 4 + m) * 16 + lkg * 4;
    const int b = be0 >> 5, e = be0 & 31;
    float4 o;
    o.x = acc[m][0] * ri;
    o.y = acc[m][1] * ri;
    o.z = acc[m][2] * ri;
    o.w = acc[m][3] * ri;
    *(float4*)&out_xi[((size_t)b * NT_ + t) * E_ + e] = o;
  }
}

// ---------------------------------------------------------------------------
extern "C" void kernel_launch(void* const* d_in, const int* in_sizes, int n_in,
                              void* d_out, int out_size, void* d_ws,
                              size_t ws_size, hipStream_t stream)
{
  const float* x       = (const float*)d_in[0];
  const float* rel_lon = (const float*)d_in[1];
  const float* rel_lat = (const float*)d_in[2];
  const float* cs      = (const float*)d_in[3];
  const float* ct      = (const float*)d_in[4];

  float* out = (float*)d_out;
  float* out_xn  = out;                                // (8,8192,10,32)
  float* out_xi  = out + (size_t)B_ * NT_ * NH_ * E_;  // (8,8192,32)
  float* out_d   = out_xi + (size_t)B_ * NT_ * E_;     // (8192,10)
  float* out_lon = out_d + (size_t)NT_ * NH_;
  float* out_lat = out_lon + (size_t)NT_ * NH_;

  int* idxbuf = (int*)d_ws;                      // 328 KB
  unsigned short* XT = (unsigned short*)out_xn;  // 4.2 MB scratch in out_xn;
                                                 // gather_kernel rewrites it.

  topk_kernel<<<NT_ / 4, 256, 0, stream>>>(rel_lon, rel_lat, out_d, out_lon,
                                           out_lat, idxbuf);
  xprep_kernel<<<dim3(NS_ / 128, B_), 256, 0, stream>>>(x, XT);
  xinter_mfma<<<NT_ / 32, 512, 0, stream>>>(XT, cs, ct, out_xi);
  gather_kernel<<<NT_, 256, 0, stream>>>(x, idxbuf, out_xn);
}

// Round 8
// 338.725 us; speedup vs baseline: 2.6626x; 1.5255x over previous
//
#include <hip/hip_runtime.h>
#include <hip/hip_bf16.h>
#include <stdint.h>

#define B_   8
#define NS_  8192
#define E_   32
#define NT_  8192
#define NH_  10
#define NCH_ 128   // NS_/64 K-chunks

typedef __bf16 bf16x8 __attribute__((ext_vector_type(8)));
typedef float  f32x4  __attribute__((ext_vector_type(4)));
typedef unsigned short ushort8_t __attribute__((ext_vector_type(8)));
typedef unsigned short ushort4_t __attribute__((ext_vector_type(4)));

static __device__ inline unsigned short f2bf(float f) {
  __hip_bfloat16 h = __float2bfloat16(f);
  return *reinterpret_cast<unsigned short*>(&h);
}
static __device__ inline float bf2f(unsigned short u) {
  __hip_bfloat16 h;
  *reinterpret_cast<unsigned short*>(&h) = u;
  return __bfloat162float(h);
}

// ---------------------------------------------------------------------------
// Kernel A: per-target-row top-10 smallest d. (VERIFIED PASSING — unchanged.)
// ---------------------------------------------------------------------------
__global__ __launch_bounds__(256) void topk_kernel(
    const float* __restrict__ rel_lon, const float* __restrict__ rel_lat,
    float* __restrict__ out_d, float* __restrict__ out_lon,
    float* __restrict__ out_lat, int* __restrict__ idx_out)
{
  const int wave = threadIdx.x >> 6;
  const int lane = threadIdx.x & 63;
  const int t = blockIdx.x * 4 + wave;
  const float* lon_row = rel_lon + (size_t)t * NS_;
  const float* lat_row = rel_lat + (size_t)t * NS_;

  unsigned long long top[NH_];
#pragma unroll
  for (int i = 0; i < NH_; ++i) top[i] = ~0ull;

  for (int c = 0; c < NS_; c += 256) {
    const int s = c + lane * 4;
    const float4 lo4 = *(const float4*)(lon_row + s);
    const float4 la4 = *(const float4*)(lat_row + s);
    const float lons[4] = {lo4.x, lo4.y, lo4.z, lo4.w};
    const float lats[4] = {la4.x, la4.y, la4.z, la4.w};
#pragma unroll
    for (int j = 0; j < 4; ++j) {
      const float d = __fsqrt_rn(__fadd_rn(__fmul_rn(lons[j], lons[j]),
                                           __fmul_rn(lats[j], lats[j])));
      unsigned long long p =
          ((unsigned long long)__float_as_uint(d) << 32) | (unsigned)(s + j);
      if (p < top[NH_ - 1]) {
#pragma unroll
        for (int i = 0; i < NH_; ++i) {
          const bool lt = p < top[i];
          const unsigned long long mn = lt ? p : top[i];
          const unsigned long long mx = lt ? top[i] : p;
          top[i] = mn;
          p = mx;
        }
      }
    }
  }

  unsigned long long resv = ~0ull;
  unsigned long long cur = top[0];
#pragma unroll
  for (int k = 0; k < NH_; ++k) {
    unsigned long long m = cur;
#pragma unroll
    for (int off = 32; off > 0; off >>= 1) {
      const unsigned long long o = __shfl_xor(m, off, 64);
      m = o < m ? o : m;
    }
    if (cur == m) {
#pragma unroll
      for (int i = 0; i < NH_ - 1; ++i) top[i] = top[i + 1];
      top[NH_ - 1] = ~0ull;
      cur = top[0];
    }
    if (lane == k) resv = m;
  }

  if (lane < NH_) {
    const unsigned s = (unsigned)(resv & 0xffffffffu);
    const float d = __uint_as_float((unsigned)(resv >> 32));
    out_d[t * NH_ + lane] = d;
    idx_out[t * NH_ + lane] = (int)s;
    out_lon[t * NH_ + lane] = lon_row[s];
    out_lat[t * NH_ + lane] = lat_row[s];
  }
}

// ---------------------------------------------------------------------------
// Kernel B: x_nearest gather. (VERIFIED PASSING — unchanged. Runs LAST.)
// ---------------------------------------------------------------------------
__global__ __launch_bounds__(256) void gather_kernel(
    const float* __restrict__ x, const int* __restrict__ idxbuf,
    float* __restrict__ out_xn)
{
  const int t = blockIdx.x;
  __shared__ int sidx[NH_];
  if (threadIdx.x < NH_) sidx[threadIdx.x] = idxbuf[t * NH_ + threadIdx.x];
  __syncthreads();
  for (int i = threadIdx.x; i < B_ * NH_ * (E_ / 4); i += 256) {  // 640 items
    const int e4 = i & 7;
    const int k = (i >> 3) % NH_;
    const int b = (i >> 3) / NH_;
    const int s = sidx[k];
    const float4 v = *(const float4*)(x + ((size_t)b * NS_ + s) * E_ + e4 * 4);
    *(float4*)(out_xn + (((size_t)b * NT_ + t) * NH_ + k) * E_ + e4 * 4) = v;
  }
}

// ---------------------------------------------------------------------------
// Kernel P: x (f32 [b][s][e]) -> XT2 (bf16, GEMM-chunked layout):
//   XT2[c][kidx][be][slot] = bf16(x[be>>5][c*64+kidx*8+slot][be&31])
//   (c = s>>6, kidx = (s>>3)&7, slot = s&7; be = b*32+e)
// This makes xinter's global_load_lds staging lane-consecutive (coalesced).
// ---------------------------------------------------------------------------
__global__ __launch_bounds__(256) void xprep_kernel(
    const float* __restrict__ x, unsigned short* __restrict__ XT2)
{
  __shared__ __align__(16) unsigned short T[32][136];  // pad: 16B-aligned rows
  const int b = blockIdx.y;
  const int s0 = blockIdx.x * 128;
  const int tid = threadIdx.x;
  const int eq = tid & 7, slq = tid >> 3;
#pragma unroll
  for (int r4 = 0; r4 < 4; ++r4) {
    const int sl = r4 * 32 + slq;
    const float4 v = *(const float4*)&x[((size_t)b * NS_ + s0 + sl) * E_ + eq * 4];
    T[eq * 4 + 0][sl] = f2bf(v.x);
    T[eq * 4 + 1][sl] = f2bf(v.y);
    T[eq * 4 + 2][sl] = f2bf(v.z);
    T[eq * 4 + 3][sl] = f2bf(v.w);
  }
  __syncthreads();
  // write: thread (r = tid&31, cq = tid>>5) stores s-range s0+cq*16 .. +16
  const int r = tid & 31, cq = tid >> 5;
  const int be = b * 32 + r;
  const int sA = s0 + cq * 16;            // aligned 8; 16 s in same 64-chunk
  const int c = sA >> 6;
  const int kA = (sA >> 3) & 7;
  unsigned short* dst = XT2 + ((size_t)(c * 8 + kA) * 256 + be) * 8;
  *(ushort8_t*)dst = *(const ushort8_t*)&T[r][cq * 16];
  // kidx+1 region is +256*8 elements away
  *(ushort8_t*)(dst + 2048) = *(const ushort8_t*)&T[r][cq * 16 + 8];
}

// ---------------------------------------------------------------------------
// Kernel C: x_inter via bf16 MFMA, double-buffered + shared B-fragments.
//   out[be][t] = (sum_s XT[be][s] * r(t,s)) / rsum[t]
// 8 waves = 4 mg (M=64 each) x 2 ng (16-t n-tiles). Per chunk (64 s):
//  - all 512 threads generate the 32t x 64s r-tile ONCE (4 r/thread,
//    round-5 bit-exact strict d2, contract off) -> bf16 Rl in B-frag layout
//  - waves stage NEXT chunk's A-tile via coalesced global_load_lds (XT2)
//  - raw s_barrier + counted waits keep stage loads in flight across the
//    mid barrier (T3-minimum pipeline).
// A/B k-indexing is identical per-lane (s = c*64+kidx*8+slot) => exact.
// ---------------------------------------------------------------------------
__global__ __launch_bounds__(512) void xinter_mfma(
    const unsigned short* __restrict__ XT2, const float* __restrict__ cs,
    const float* __restrict__ ct, float* __restrict__ out_xi)
{
#pragma clang fp contract(off)
  __shared__ __align__(16) unsigned short Xl[2][8][256][8];  // 64 KB
  __shared__ __align__(16) unsigned short Rl[2][8][16][8];   // 4 KB [ng][kidx][lcol][slot]
  __shared__ float RsumP[16][32];
  __shared__ float RsumInv[32];

  const int tid = threadIdx.x;
  const int w = tid >> 6, l = tid & 63;
  const int mg = w >> 1, ng = w & 1;
  const int lcol = l & 15, lkg = l >> 4;
  const int t0 = blockIdx.x * 32;

  // --- gen-role indices: thread computes r for t=t0+gt, s-quad gq ---
  const int gt = tid & 31;
  const int gq = tid >> 5;
  const int gng = gt >> 4, glc = gt & 15;
  const int gk = gq >> 1;              // kidx
  const int gsl = (gq & 1) * 4;        // slot base
  const float2 ctg = ((const float2*)ct)[t0 + gt];
  const float t2g = ctg.x * ctg.x + ctg.y * ctg.y;   // strict rn
  float rpart = 0.f;

  // --- compute-role target ---
  const int t = t0 + ng * 16 + lcol;

  f32x4 acc[4];
#pragma unroll
  for (int m = 0; m < 4; ++m)
#pragma unroll
    for (int j = 0; j < 4; ++j) acc[m][j] = 0.f;

#define STAGE_CHUNK(buf, ch)                                                 \
  {                                                                          \
    const unsigned short* gsrc =                                             \
        XT2 + ((size_t)(ch) * 8 + w) * 2048 + (size_t)l * 8;                 \
    _Pragma("unroll")                                                        \
    for (int bg = 0; bg < 4; ++bg) {                                         \
      __builtin_amdgcn_global_load_lds(                                      \
          (const __attribute__((address_space(1))) void*)(gsrc + bg * 512),  \
          (__attribute__((address_space(3))) void*)&Xl[buf][w][bg * 64][0],  \
          16, 0, 0);                                                         \
    }                                                                        \
  }

  // prologue: stage chunk 0 into buffer 0
  STAGE_CHUNK(0, 0);
  asm volatile("s_waitcnt vmcnt(0)" ::: "memory");
  __builtin_amdgcn_s_barrier();

  int cur = 0;
  for (int c = 0; c < NCH_; ++c) {
    if (c + 1 < NCH_) STAGE_CHUNK(cur ^ 1, c + 1);

    // ---- generate 4 r-values (strict, bit-exact d2 path) ----
    {
      const int sb = c * 64 + gq * 4;
      const float4 cA = *(const float4*)&cs[2 * sb];
      const float4 cB = *(const float4*)&cs[2 * sb + 4];
      const float sxv[4] = {cA.x, cA.z, cB.x, cB.z};
      const float syv[4] = {cA.y, cA.w, cB.y, cB.w};
      ushort4_t ro;
#pragma unroll
      for (int j = 0; j < 4; ++j) {
        const float sx = sxv[j], sy = syv[j];
        const float s2 = sx * sx + sy * sy;        // strict rn
        const float p0 = ctg.x * sx;               // strict rn product, k=0
        const float dot = fmaf(ctg.y, sy, p0);     // explicit fma, k=1
        const float ts = t2g + s2;                 // strict rn
        float d2 = ts - 2.0f * dot;                // 2*dot exact; strict sub
        d2 = fmaxf(d2, 1e-12f);
        const float r = __builtin_amdgcn_rsqf(d2);
        const unsigned short ub = f2bf(r);
        ro[j] = ub;
        rpart += bf2f(ub);
      }
      *(ushort4_t*)&Rl[gng][gk][glc][gsl] = ro;    // 8B ds_write
    }
    asm volatile("s_waitcnt lgkmcnt(0)" ::: "memory");
    __builtin_amdgcn_s_barrier();                  // Rl visible; Xl[cur] ready

    // ---- compute ----
#pragma unroll
    for (int half = 0; half < 2; ++half) {
      const bf16x8 Bf = *(const bf16x8*)&Rl[ng][half * 4 + lkg][lcol][0];
#pragma unroll
      for (int m = 0; m < 4; ++m) {
        const bf16x8 a =
            *(const bf16x8*)&Xl[cur][half * 4 + lkg][(mg * 4 + m) * 16 + lcol][0];
        acc[m] = __builtin_amdgcn_mfma_f32_16x16x32_bf16(a, Bf, acc[m], 0, 0, 0);
      }
    }

    asm volatile("s_waitcnt vmcnt(0)" ::: "memory");
    __builtin_amdgcn_s_barrier();                  // Xl[nxt] complete
    cur ^= 1;
  }
#undef STAGE_CHUNK

  // ---- rsum reduction: 16 partials per t ----
  RsumP[gq][gt] = rpart;
  asm volatile("s_waitcnt lgkmcnt(0)" ::: "memory");
  __builtin_amdgcn_s_barrier();
  if (tid < 32) {
    float ssum = 0.f;
#pragma unroll
    for (int q = 0; q < 16; ++q) ssum += RsumP[q][tid];
    RsumInv[tid] = 1.0f / ssum;
  }
  asm volatile("s_waitcnt lgkmcnt(0)" ::: "memory");
  __builtin_amdgcn_s_barrier();
  const float ri = RsumInv[ng * 16 + lcol];

  // C/D layout: lane l reg j -> row(be) = lkg*4 + j, col(t) = lcol.
#pragma unroll
  for (int m = 0; m < 4; ++m) {
    const int be0 = (mg * 4 + m) * 16 + lkg * 4;
    const int b = be0 >> 5, e = be0 & 31;
    float4 o;
    o.x = acc[m][0] * ri;
    o.y = acc[m][1] * ri;
    o.z = acc[m][2] * ri;
    o.w = acc[m][3] * ri;
    *(float4*)&out_xi[((size_t)b * NT_ + t) * E_ + e] = o;
  }
}

// ---------------------------------------------------------------------------
extern "C" void kernel_launch(void* const* d_in, const int* in_sizes, int n_in,
                              void* d_out, int out_size, void* d_ws,
                              size_t ws_size, hipStream_t stream)
{
  const float* x       = (const float*)d_in[0];
  const float* rel_lon = (const float*)d_in[1];
  const float* rel_lat = (const float*)d_in[2];
  const float* cs      = (const float*)d_in[3];
  const float* ct      = (const float*)d_in[4];

  float* out = (float*)d_out;
  float* out_xn  = out;                                // (8,8192,10,32)
  float* out_xi  = out + (size_t)B_ * NT_ * NH_ * E_;  // (8,8192,32)
  float* out_d   = out_xi + (size_t)B_ * NT_ * E_;     // (8192,10)
  float* out_lon = out_d + (size_t)NT_ * NH_;
  float* out_lat = out_lon + (size_t)NT_ * NH_;

  int* idxbuf = (int*)d_ws;                       // 328 KB
  unsigned short* XT2 = (unsigned short*)out_xn;  // 4 MB scratch in out_xn;
                                                  // gather_kernel rewrites it.

  topk_kernel<<<NT_ / 4, 256, 0, stream>>>(rel_lon, rel_lat, out_d, out_lon,
                                           out_lat, idxbuf);
  xprep_kernel<<<dim3(NS_ / 128, B_), 256, 0, stream>>>(x, XT2);
  xinter_mfma<<<NT_ / 32, 512, 0, stream>>>(XT2, cs, ct, out_xi);
  gather_kernel<<<NT_, 256, 0, stream>>>(x, idxbuf, out_xn);
}